// Round 3
// baseline (795.970 us; speedup 1.0000x reference)
//
#include <hip/hip_runtime.h>

#define SS 4
#define NH 6
#define NWIN 2048

typedef unsigned short u16;
typedef __attribute__((ext_vector_type(8))) short bf8;
typedef __attribute__((ext_vector_type(4))) float f4;

__device__ __forceinline__ u16 f2bf(float f) {
  unsigned int x = __builtin_bit_cast(unsigned int, f);
  unsigned int r = x + 0x7fffu + ((x >> 16) & 1u);
  return (u16)(r >> 16);
}
__device__ __forceinline__ unsigned int pk2(float a, float b) {
  return (unsigned int)f2bf(a) | ((unsigned int)f2bf(b) << 16);
}

// Inline exact-GELU: 0.5*v*(1+erf(v/sqrt2)) with Abramowitz-Stegun 7.1.26 erf
// (|err| <= 1.5e-7 — far below bf16 rounding). Pure VALU, no libm call, so
// nothing is live across a call boundary (the erff() call was forcing the
// compiler to spill acc2/af/w1/w2 every slab: 1.15 GB of scratch HBM writes).
__device__ __forceinline__ float gelu_exact(float v) {
  float u = v * 0.70710678118654752f;
  float a = __builtin_fabsf(u);
  float t = __builtin_amdgcn_rcpf(1.f + 0.3275911f * a);
  float poly = t * (0.254829592f + t * (-0.284496736f + t * (1.421413741f +
               t * (-1.453152027f + t * 1.061405429f))));
  float e = __expf(-a * a);
  float erf_a = 1.f - poly * e;
  float erf_u = (u < 0.f) ? -erf_a : erf_a;
  return 0.5f * v * (1.f + erf_u);
}

// LDS read helper: byte-offset addressing (offsets are 16B-aligned)
#define LDSB(base, off) (*(const bf8*)((const char*)(base) + (off)))

// Build an A/B-fragment (row = lr, k = quad*8 + e) from quad-transposed
// register state (see r1 derivation; verified-passing layout).
__device__ __forceinline__ bf8 fragq(unsigned p00, unsigned p01,
                                     unsigned p10, unsigned p11,
                                     int L0, int L1, bool selhi) {
  unsigned a0 = (unsigned)__shfl((int)p00, L0);
  unsigned a1 = (unsigned)__shfl((int)p01, L0);
  unsigned b0 = (unsigned)__shfl((int)p10, L0);
  unsigned b1 = (unsigned)__shfl((int)p11, L0);
  unsigned c0 = (unsigned)__shfl((int)p00, L1);
  unsigned c1 = (unsigned)__shfl((int)p01, L1);
  unsigned d0 = (unsigned)__shfl((int)p10, L1);
  unsigned d1 = (unsigned)__shfl((int)p11, L1);
  uint4 t;
  t.x = selhi ? b0 : a0;
  t.y = selhi ? b1 : a1;
  t.z = selhi ? d0 : c0;
  t.w = selhi ? d1 : c1;
  return __builtin_bit_cast(bf8, t);
}

// ---- prep: f32 [K][N] -> bf16 transposed [N][K], optional scale for n<scale_n ----
__global__ __launch_bounds__(256) void k_prep(
    const float* __restrict__ src, u16* __restrict__ dst,
    int K, int N, int scale_n, float scale)
{
  int idx = blockIdx.x * 256 + threadIdx.x;
  int total = (K >> 2) * N;
  if (idx >= total) return;
  int n = idx % N;
  int kq = (idx / N) << 2;
  float s = (n < scale_n) ? scale : 1.f;
  ushort4 o;
  o.x = f2bf(src[(size_t)(kq + 0) * N + n] * s);
  o.y = f2bf(src[(size_t)(kq + 1) * N + n] * s);
  o.z = f2bf(src[(size_t)(kq + 2) * N + n] * s);
  o.w = f2bf(src[(size_t)(kq + 3) * N + n] * s);
  *(ushort4*)(dst + (size_t)n * K + kq) = o;
}

// ---- K1: roll+partition+QKV+attention+proj+reverse+roll+residual ----
// Register-resident Q/P/O (swapped MFMA + quad-permute), K/V in swizzled LDS.
// Weights: T14 async staging -> 24KB LDS slab, prefetch-next-in-regs.
// LDS 72KB -> 2 blocks/CU.  (unchanged from r2 — isolating the k_mlp fix)
__global__ __launch_bounds__(256, 2) void k_win(
    const float* __restrict__ x, const u16* __restrict__ qkvT,
    const float* __restrict__ qkv_b, const float* __restrict__ rpb,
    const u16* __restrict__ projT, const float* __restrict__ proj_b,
    float* __restrict__ out)
{
  __shared__ short KsB[64 * 192];   // K [token][chan], rows 384B, XOR-swizzled
  __shared__ short VtB[192 * 64];   // V^T [chan][token], rows 128B, swizzled
  __shared__ short WtB[64 * 192];   // weight slab [n_local][k], swizzled

  const int w = blockIdx.x;
  const int b = w >> 6, wh = (w >> 3) & 7, wwi = w & 7;
  const int tid = threadIdx.x;
  const int wave = tid >> 6, lane = tid & 63, quad = lane >> 4, lr = lane & 15;
  const int L0 = (quad & 1) * 32 + lr, L1 = L0 + 16;
  const bool selhi = (quad >> 1) != 0;
  const int xlr = (lr & 7) << 4;

  const char* qkvB = (const char*)qkvT;
  const char* projB = (const char*)projT;
  const int a0 = tid * 16;

  // staging offsets (loop-invariant): LDS dst byte for linear chunk byte a
  int ldsW[6];
#pragma unroll
  for (int i = 0; i < 6; ++i) {
    int a = a0 + i * 4096;
    int row = a / 384, col = a - row * 384;
    ldsW[i] = row * 384 + (col ^ ((row & 7) << 4));
  }

  // prefetch weight slab 0 into regs (L2), before the HBM x loads
  uint4 wreg[6];
#pragma unroll
  for (int i = 0; i < 6; ++i) wreg[i] = *(const uint4*)(qkvB + a0 + i * 4096);

  // Phase A: A-fragments of rolled window straight into registers
  bf8 af[6];
  {
    int token = wave * 16 + lr;
    int hs = (wh * 8 + (token >> 3) + SS) & 63;
    int ws2 = (wwi * 8 + (token & 7) + SS) & 63;
    const float* base = x + ((size_t)b * 4096 + hs * 64 + ws2) * 192 + quad * 8;
#pragma unroll
    for (int kc = 0; kc < 6; ++kc) {
      float4 lo = *(const float4*)(base + kc * 32);
      float4 hi = *(const float4*)(base + kc * 32 + 4);
      bf8 v;
      v[0] = (short)f2bf(lo.x); v[1] = (short)f2bf(lo.y);
      v[2] = (short)f2bf(lo.z); v[3] = (short)f2bf(lo.w);
      v[4] = (short)f2bf(hi.x); v[5] = (short)f2bf(hi.y);
      v[6] = (short)f2bf(hi.z); v[7] = (short)f2bf(hi.w);
      af[kc] = v;
    }
  }

  // publish current wreg -> Wt, prefetch next slab into wreg (T14 split)
  auto stage = [&](const char* nsrc) {
    __syncthreads();                       // prior slab's readers done
#pragma unroll
    for (int i = 0; i < 6; ++i) *(uint4*)((char*)WtB + ldsW[i]) = wreg[i];
    if (nsrc) {
#pragma unroll
      for (int i = 0; i < 6; ++i) wreg[i] = *(const uint4*)(nsrc + a0 + i * 4096);
    }
    __syncthreads();                       // Wt ready
  };

  const float scale = 0.17677669529663687f;

  // Phase B1: Q slabs 0..2, SWAPPED GEMM -> qf frags (token = lr)
  bf8 qf[6];
  for (int s = 0; s < 3; ++s) {
    stage(qkvB + (size_t)(s + 1) * 24576);
    f4 qa[4];
#pragma unroll
    for (int i = 0; i < 4; ++i) qa[i] = (f4){0.f, 0.f, 0.f, 0.f};
#pragma unroll
    for (int kc = 0; kc < 6; ++kc)
#pragma unroll
      for (int nt = 0; nt < 4; ++nt) {
        bf8 wf = LDSB(WtB, (nt * 16 + lr) * 384 + ((kc * 64 + quad * 16) ^ xlr));
        qa[nt] = __builtin_amdgcn_mfma_f32_16x16x32_bf16(wf, af[kc], qa[nt], 0, 0, 0);
      }
    unsigned pq[4][2];
#pragma unroll
    for (int nt = 0; nt < 4; ++nt) {
      float4 bv = *(const float4*)(qkv_b + s * 64 + nt * 16 + quad * 4);
      pq[nt][0] = pk2(qa[nt][0] + bv.x * scale, qa[nt][1] + bv.y * scale);
      pq[nt][1] = pk2(qa[nt][2] + bv.z * scale, qa[nt][3] + bv.w * scale);
    }
#pragma unroll
    for (int hh = 0; hh < 2; ++hh)
      qf[s * 2 + hh] = fragq(pq[hh * 2][0], pq[hh * 2][1],
                             pq[hh * 2 + 1][0], pq[hh * 2 + 1][1], L0, L1, selhi);
  }

  // Phase B2: K slabs 3..5, SWAPPED -> swizzled Ks[token][chan]
  for (int s = 0; s < 3; ++s) {
    stage(qkvB + (size_t)(s + 4) * 24576);
    f4 ka[4];
#pragma unroll
    for (int i = 0; i < 4; ++i) ka[i] = (f4){0.f, 0.f, 0.f, 0.f};
#pragma unroll
    for (int kc = 0; kc < 6; ++kc)
#pragma unroll
      for (int nt = 0; nt < 4; ++nt) {
        bf8 wf = LDSB(WtB, (nt * 16 + lr) * 384 + ((kc * 64 + quad * 16) ^ xlr));
        ka[nt] = __builtin_amdgcn_mfma_f32_16x16x32_bf16(wf, af[kc], ka[nt], 0, 0, 0);
      }
#pragma unroll
    for (int nt = 0; nt < 4; ++nt) {
      float4 bv = *(const float4*)(qkv_b + 192 + s * 64 + nt * 16 + quad * 4);
      uint2 st;
      st.x = pk2(ka[nt][0] + bv.x, ka[nt][1] + bv.y);
      st.y = pk2(ka[nt][2] + bv.z, ka[nt][3] + bv.w);
      *(uint2*)((char*)KsB + (wave * 16 + lr) * 384 +
                ((s * 128 + nt * 32 + quad * 8) ^ xlr)) = st;
    }
  }

  // Phase B3: V slabs 6..8, NORMAL -> swizzled Vt[chan][token]
  for (int s = 0; s < 3; ++s) {
    stage(s < 2 ? qkvB + (size_t)(s + 7) * 24576 : projB);
    f4 va[4];
#pragma unroll
    for (int i = 0; i < 4; ++i) va[i] = (f4){0.f, 0.f, 0.f, 0.f};
#pragma unroll
    for (int kc = 0; kc < 6; ++kc)
#pragma unroll
      for (int nt = 0; nt < 4; ++nt) {
        bf8 wf = LDSB(WtB, (nt * 16 + lr) * 384 + ((kc * 64 + quad * 16) ^ xlr));
        va[nt] = __builtin_amdgcn_mfma_f32_16x16x32_bf16(af[kc], wf, va[nt], 0, 0, 0);
      }
#pragma unroll
    for (int nt = 0; nt < 4; ++nt) {
      float bias = qkv_b[384 + s * 64 + nt * 16 + lr];
      uint2 st;
      st.x = pk2(va[nt][0] + bias, va[nt][1] + bias);
      st.y = pk2(va[nt][2] + bias, va[nt][3] + bias);
      *(uint2*)((char*)VtB + (size_t)(s * 64 + nt * 16 + lr) * 128 +
                ((wave * 32 + quad * 8) ^ xlr)) = st;
    }
  }

  // publish proj slab 0, prefetch proj slab 1; first barrier also publishes Ks/Vt
  stage(projB + 24576);

  // Phase C: attention, fully in-register softmax (query = lr)
  const int q_tok = wave * 16 + lr;
  const int qh3 = q_tok >> 3, qw3 = q_tok & 7;
  int lab_q;
  {
    int ph_r = wh * 8 + qh3, pw_r = wwi * 8 + qw3;
    lab_q = (ph_r < 56 ? 0 : (ph_r < 60 ? 1 : 2)) * 3 +
            (pw_r < 56 ? 0 : (pw_r < 60 ? 1 : 2));
  }
  int ridx[4][4]; float msk[4][4];
#pragma unroll
  for (int nt = 0; nt < 4; ++nt)
#pragma unroll
    for (int r = 0; r < 4; ++r) {
      int key = nt * 16 + quad * 4 + r;
      int kh = key >> 3, kw = key & 7;
      ridx[nt][r] = ((qh3 - kh + 7) * 15 + (qw3 - kw + 7)) * NH;
      int ph_c = wh * 8 + kh, pw_c = wwi * 8 + kw;
      int lab_k = (ph_c < 56 ? 0 : (ph_c < 60 ? 1 : 2)) * 3 +
                  (pw_c < 56 ? 0 : (pw_c < 60 ? 1 : 2));
      msk[nt][r] = (lab_q != lab_k) ? -100.f : 0.f;
    }

  unsigned obf[6][4];
#pragma unroll
  for (int h = 0; h < 6; ++h) {
    f4 sa[4];
#pragma unroll
    for (int i = 0; i < 4; ++i) sa[i] = (f4){0.f, 0.f, 0.f, 0.f};
#pragma unroll
    for (int nt = 0; nt < 4; ++nt) {
      bf8 kfr = LDSB(KsB, (nt * 16 + lr) * 384 + ((h * 64 + quad * 16) ^ xlr));
      sa[nt] = __builtin_amdgcn_mfma_f32_16x16x32_bf16(kfr, qf[h], sa[nt], 0, 0, 0);
    }
    float p[4][4]; float mx = -1e30f;
#pragma unroll
    for (int nt = 0; nt < 4; ++nt)
#pragma unroll
      for (int r = 0; r < 4; ++r) {
        float v = sa[nt][r] + rpb[ridx[nt][r] + h] + msk[nt][r];
        p[nt][r] = v; mx = fmaxf(mx, v);
      }
    mx = fmaxf(mx, __shfl_xor(mx, 16));
    mx = fmaxf(mx, __shfl_xor(mx, 32));
    float sum = 0.f;
#pragma unroll
    for (int nt = 0; nt < 4; ++nt)
#pragma unroll
      for (int r = 0; r < 4; ++r) {
        float e = __expf(p[nt][r] - mx);
        p[nt][r] = e; sum += e;
      }
    sum += __shfl_xor(sum, 16);
    sum += __shfl_xor(sum, 32);
    float inv = 1.f / sum;
    unsigned pp[4][2];
#pragma unroll
    for (int nt = 0; nt < 4; ++nt) {
      pp[nt][0] = pk2(p[nt][0] * inv, p[nt][1] * inv);
      pp[nt][1] = pk2(p[nt][2] * inv, p[nt][3] * inv);
    }
    f4 o0 = (f4){0.f, 0.f, 0.f, 0.f}, o1 = (f4){0.f, 0.f, 0.f, 0.f};
#pragma unroll
    for (int kc = 0; kc < 2; ++kc) {
      bf8 pf = fragq(pp[kc * 2][0], pp[kc * 2][1],
                     pp[kc * 2 + 1][0], pp[kc * 2 + 1][1], L0, L1, selhi);
      bf8 v0 = LDSB(VtB, (size_t)(h * 32 + lr) * 128 + ((kc * 64 + quad * 16) ^ xlr));
      bf8 v1 = LDSB(VtB, (size_t)(h * 32 + 16 + lr) * 128 + ((kc * 64 + quad * 16) ^ xlr));
      o0 = __builtin_amdgcn_mfma_f32_16x16x32_bf16(v0, pf, o0, 0, 0, 0);
      o1 = __builtin_amdgcn_mfma_f32_16x16x32_bf16(v1, pf, o1, 0, 0, 0);
    }
    obf[h][0] = pk2(o0[0], o0[1]); obf[h][1] = pk2(o0[2], o0[3]);
    obf[h][2] = pk2(o1[0], o1[1]); obf[h][3] = pk2(o1[2], o1[3]);
  }

  // Phase D: proj from register O; weight slabs via same staging machinery
  bf8 of[6];
#pragma unroll
  for (int kc = 0; kc < 6; ++kc)
    of[kc] = fragq(obf[kc][0], obf[kc][1], obf[kc][2], obf[kc][3], L0, L1, selhi);

  for (int s3 = 0; s3 < 3; ++s3) {
    f4 acc[4];
#pragma unroll
    for (int i = 0; i < 4; ++i) acc[i] = (f4){0.f, 0.f, 0.f, 0.f};
#pragma unroll
    for (int kc = 0; kc < 6; ++kc)
#pragma unroll
      for (int nt = 0; nt < 4; ++nt) {
        bf8 wf = LDSB(WtB, (nt * 16 + lr) * 384 + ((kc * 64 + quad * 16) ^ xlr));
        acc[nt] = __builtin_amdgcn_mfma_f32_16x16x32_bf16(of[kc], wf, acc[nt], 0, 0, 0);
      }
#pragma unroll
    for (int nt = 0; nt < 4; ++nt) {
      int c = s3 * 64 + nt * 16 + lr;
      float bias = proj_b[c];
#pragma unroll
      for (int r = 0; r < 4; ++r) {
        int row = wave * 16 + quad * 4 + r;
        int ho = (wh * 8 + (row >> 3) + SS) & 63;
        int wo = (wwi * 8 + (row & 7) + SS) & 63;
        size_t off = ((size_t)b * 4096 + ho * 64 + wo) * 192 + c;
        out[off] = acc[nt][r] + bias + x[off];
      }
    }
    if (s3 == 0)      stage(projB + (size_t)2 * 24576);
    else if (s3 == 1) stage(nullptr);
  }
}

// ---- K2: fused FC1+GELU+FC2+residual ----
// H register-resident (swapped FC1 + quad-permute); weights LDS-staged with
// T14 async split. Inline GELU (no libm call -> no spills).
__global__ __launch_bounds__(256, 2) void k_mlp(
    const u16* __restrict__ fc1T, const float* __restrict__ fc1_b,
    const u16* __restrict__ fc2T, const float* __restrict__ fc2_b,
    float* __restrict__ out)
{
  __shared__ short Wl1[64 * 192];   // fc1 slab [n_local][k=192], swizzled
  __shared__ short Wl2[192 * 64];   // fc2 slab [n=192][k_local=64], swizzled

  const int blk = blockIdx.x;
  const int tid = threadIdx.x;
  const int wave = tid >> 6, lane = tid & 63, quad = lane >> 4, lr = lane & 15;
  const int L0 = (quad & 1) * 32 + lr, L1 = L0 + 16;
  const bool selhi = (quad >> 1) != 0;
  const int xlr = (lr & 7) << 4;
  const size_t r0 = (size_t)blk * 64;

  const char* fc1B = (const char*)fc1T;
  const char* fc2B = (const char*)fc2T;
  const int a0 = tid * 16;

  int lds1[6], lds2[6], g2[6];
#pragma unroll
  for (int i = 0; i < 6; ++i) {
    int A = a0 + i * 4096;
    int row = A / 384, col = A - row * 384;
    lds1[i] = row * 384 + (col ^ ((row & 7) << 4));
    int r2 = A >> 7, c2 = A & 127;
    g2[i] = r2 * 1536 + c2;
    lds2[i] = r2 * 128 + (c2 ^ ((r2 & 7) << 4));
  }

  // prefetch slab 0 weights (L2) before the HBM activation loads
  uint4 w1[6], w2[6];
#pragma unroll
  for (int i = 0; i < 6; ++i) w1[i] = *(const uint4*)(fc1B + a0 + i * 4096);
#pragma unroll
  for (int i = 0; i < 6; ++i) w2[i] = *(const uint4*)(fc2B + g2[i]);

  // A-fragments of x1 straight from global (f32 -> bf16 regs)
  bf8 af[6];
  {
    const float* base = out + (r0 + wave * 16 + lr) * 192 + quad * 8;
#pragma unroll
    for (int kc = 0; kc < 6; ++kc) {
      float4 lo = *(const float4*)(base + kc * 32);
      float4 hi = *(const float4*)(base + kc * 32 + 4);
      bf8 v;
      v[0] = (short)f2bf(lo.x); v[1] = (short)f2bf(lo.y);
      v[2] = (short)f2bf(lo.z); v[3] = (short)f2bf(lo.w);
      v[4] = (short)f2bf(hi.x); v[5] = (short)f2bf(hi.y);
      v[6] = (short)f2bf(hi.z); v[7] = (short)f2bf(hi.w);
      af[kc] = v;
    }
  }

  f4 acc2[12];
#pragma unroll
  for (int i = 0; i < 12; ++i) acc2[i] = (f4){0.f, 0.f, 0.f, 0.f};

#pragma unroll 1
  for (int s = 0; s < 12; ++s) {
    __syncthreads();                    // previous slab's readers done
#pragma unroll
    for (int i = 0; i < 6; ++i) *(uint4*)((char*)Wl1 + lds1[i]) = w1[i];
#pragma unroll
    for (int i = 0; i < 6; ++i) *(uint4*)((char*)Wl2 + lds2[i]) = w2[i];
    if (s < 11) {                       // prefetch next slab, hidden under MFMAs
#pragma unroll
      for (int i = 0; i < 6; ++i)
        w1[i] = *(const uint4*)(fc1B + (size_t)(s + 1) * 24576 + a0 + i * 4096);
#pragma unroll
      for (int i = 0; i < 6; ++i)
        w2[i] = *(const uint4*)(fc2B + (size_t)(s + 1) * 128 + g2[i]);
    }
    __syncthreads();                    // slab ready

    // FC1 slab, SWAPPED -> H^T[hchan][token=lr] in regs
    f4 ha[4];
#pragma unroll
    for (int i = 0; i < 4; ++i) ha[i] = (f4){0.f, 0.f, 0.f, 0.f};
#pragma unroll
    for (int kc = 0; kc < 6; ++kc)
#pragma unroll
      for (int nt = 0; nt < 4; ++nt) {
        bf8 wf = LDSB(Wl1, (nt * 16 + lr) * 384 + ((kc * 64 + quad * 16) ^ xlr));
        ha[nt] = __builtin_amdgcn_mfma_f32_16x16x32_bf16(wf, af[kc], ha[nt], 0, 0, 0);
      }
    unsigned hp[4][2];
#pragma unroll
    for (int nt = 0; nt < 4; ++nt) {
      float4 bv = *(const float4*)(fc1_b + s * 64 + nt * 16 + quad * 4);
      float g0 = gelu_exact(ha[nt][0] + bv.x);
      float g1 = gelu_exact(ha[nt][1] + bv.y);
      float g2_ = gelu_exact(ha[nt][2] + bv.z);
      float g3 = gelu_exact(ha[nt][3] + bv.w);
      hp[nt][0] = pk2(g0, g1);
      hp[nt][1] = pk2(g2_, g3);
    }
    // FC2 partial accumulation (H via quad-permute)
#pragma unroll
    for (int kc2 = 0; kc2 < 2; ++kc2) {
      bf8 hf = fragq(hp[kc2 * 2][0], hp[kc2 * 2][1],
                     hp[kc2 * 2 + 1][0], hp[kc2 * 2 + 1][1], L0, L1, selhi);
#pragma unroll
      for (int nto = 0; nto < 12; ++nto) {
        bf8 wf = LDSB(Wl2, (nto * 16 + lr) * 128 + ((kc2 * 64 + quad * 16) ^ xlr));
        acc2[nto] = __builtin_amdgcn_mfma_f32_16x16x32_bf16(hf, wf, acc2[nto], 0, 0, 0);
      }
    }
  }

  // epilogue: + bias + residual (f32 re-read), in-place
#pragma unroll
  for (int nt = 0; nt < 12; ++nt) {
    int c = nt * 16 + lr;
    float bias = fc2_b[c];
#pragma unroll
    for (int r = 0; r < 4; ++r) {
      int row = wave * 16 + quad * 4 + r;
      size_t off = (r0 + row) * 192 + c;
      out[off] = acc2[nt][r] + bias + out[off];
    }
  }
}

extern "C" void kernel_launch(void* const* d_in, const int* in_sizes, int n_in,
                              void* d_out, int out_size, void* d_ws, size_t ws_size,
                              hipStream_t stream)
{
  const float* x      = (const float*)d_in[0];
  const float* rpb    = (const float*)d_in[1];
  const float* qkv_w  = (const float*)d_in[2];
  const float* qkv_b  = (const float*)d_in[3];
  const float* proj_w = (const float*)d_in[4];
  const float* proj_b = (const float*)d_in[5];
  const float* fc1_w  = (const float*)d_in[6];
  const float* fc1_b  = (const float*)d_in[7];
  const float* fc2_w  = (const float*)d_in[8];
  const float* fc2_b  = (const float*)d_in[9];
  float* out = (float*)d_out;

  // bf16 transposed weights in workspace (885 KB total)
  u16* qkvT = (u16*)d_ws;                 // [576][192]
  u16* projT = qkvT + 576 * 192;          // [192][192]
  u16* fc1T  = projT + 192 * 192;         // [768][192]
  u16* fc2T  = fc1T + 768 * 192;          // [192][768]

  const float scale = 0.17677669529663687f;  // 32^-0.5 baked into W_q
  k_prep<<<108, 256, 0, stream>>>(qkv_w, qkvT, 192, 576, 192, scale);
  k_prep<<< 36, 256, 0, stream>>>(proj_w, projT, 192, 192, 0, 1.f);
  k_prep<<<144, 256, 0, stream>>>(fc1_w, fc1T, 192, 768, 0, 1.f);
  k_prep<<<144, 256, 0, stream>>>(fc2_w, fc2T, 768, 192, 0, 1.f);

  k_win<<<dim3(NWIN), 256, 0, stream>>>(x, qkvT, qkv_b, rpb, projT, proj_b, out);
  k_mlp<<<dim3(NWIN), 256, 0, stream>>>(fc1T, fc1_b, fc2T, fc2_b, out);
}

// Round 4
// 592.652 us; speedup vs baseline: 1.3431x; 1.3431x over previous
//
#include <hip/hip_runtime.h>

#define SS 4
#define NH 6
#define NWIN 2048

typedef unsigned short u16;
typedef __attribute__((ext_vector_type(8))) short bf8;
typedef __attribute__((ext_vector_type(4))) float f4;

__device__ __forceinline__ u16 f2bf(float f) {
  unsigned int x = __builtin_bit_cast(unsigned int, f);
  unsigned int r = x + 0x7fffu + ((x >> 16) & 1u);
  return (u16)(r >> 16);
}
__device__ __forceinline__ unsigned int pk2(float a, float b) {
  return (unsigned int)f2bf(a) | ((unsigned int)f2bf(b) << 16);
}

// Inline exact-GELU (Abramowitz-Stegun 7.1.26 erf, |err|<=1.5e-7): pure VALU.
__device__ __forceinline__ float gelu_exact(float v) {
  float u = v * 0.70710678118654752f;
  float a = __builtin_fabsf(u);
  float t = __builtin_amdgcn_rcpf(1.f + 0.3275911f * a);
  float poly = t * (0.254829592f + t * (-0.284496736f + t * (1.421413741f +
               t * (-1.453152027f + t * 1.061405429f))));
  float e = __expf(-a * a);
  float erf_a = 1.f - poly * e;
  float erf_u = (u < 0.f) ? -erf_a : erf_a;
  return 0.5f * v * (1.f + erf_u);
}

// LDS read helper: byte-offset addressing (offsets are 16B-aligned)
#define LDSB(base, off) (*(const bf8*)((const char*)(base) + (off)))

// Build an A/B-fragment (row = lr, k = quad*8 + e) from quad-transposed
// register state (verified-passing layout, r1).
__device__ __forceinline__ bf8 fragq(unsigned p00, unsigned p01,
                                     unsigned p10, unsigned p11,
                                     int L0, int L1, bool selhi) {
  unsigned a0 = (unsigned)__shfl((int)p00, L0);
  unsigned a1 = (unsigned)__shfl((int)p01, L0);
  unsigned b0 = (unsigned)__shfl((int)p10, L0);
  unsigned b1 = (unsigned)__shfl((int)p11, L0);
  unsigned c0 = (unsigned)__shfl((int)p00, L1);
  unsigned c1 = (unsigned)__shfl((int)p01, L1);
  unsigned d0 = (unsigned)__shfl((int)p10, L1);
  unsigned d1 = (unsigned)__shfl((int)p11, L1);
  uint4 t;
  t.x = selhi ? b0 : a0;
  t.y = selhi ? b1 : a1;
  t.z = selhi ? d0 : c0;
  t.w = selhi ? d1 : c1;
  return __builtin_bit_cast(bf8, t);
}

// ---- prep: f32 [K][N] -> bf16 transposed [N][K], optional scale for n<scale_n ----
__global__ __launch_bounds__(256) void k_prep(
    const float* __restrict__ src, u16* __restrict__ dst,
    int K, int N, int scale_n, float scale)
{
  int idx = blockIdx.x * 256 + threadIdx.x;
  int total = (K >> 2) * N;
  if (idx >= total) return;
  int n = idx % N;
  int kq = (idx / N) << 2;
  float s = (n < scale_n) ? scale : 1.f;
  ushort4 o;
  o.x = f2bf(src[(size_t)(kq + 0) * N + n] * s);
  o.y = f2bf(src[(size_t)(kq + 1) * N + n] * s);
  o.z = f2bf(src[(size_t)(kq + 2) * N + n] * s);
  o.w = f2bf(src[(size_t)(kq + 3) * N + n] * s);
  *(ushort4*)(dst + (size_t)n * K + kq) = o;
}

// ---- K1: roll+partition+QKV+attention+proj+reverse+roll+residual ----
// Register-resident Q/P/O (swapped MFMA + quad-permute), K/V in swizzled LDS.
// Weight staging: load-inside-barriers (r0-proven — NO cross-slab prefetch
// registers; the w/wreg prefetch form caused per-slab scratch spills =
// 1.2 GB/dispatch of HBM writes). LDS 72KB -> 2 blocks/CU.
__global__ __launch_bounds__(256, 2) void k_win(
    const float* __restrict__ x, const u16* __restrict__ qkvT,
    const float* __restrict__ qkv_b, const float* __restrict__ rpb,
    const u16* __restrict__ projT, const float* __restrict__ proj_b,
    float* __restrict__ out)
{
  __shared__ short KsB[64 * 192];   // K [token][chan], rows 384B, XOR-swizzled
  __shared__ short VtB[192 * 64];   // V^T [chan][token], rows 128B, swizzled
  __shared__ short WtB[64 * 192];   // weight slab [n_local][k], swizzled

  const int w = blockIdx.x;
  const int b = w >> 6, wh = (w >> 3) & 7, wwi = w & 7;
  const int tid = threadIdx.x;
  const int wave = tid >> 6, lane = tid & 63, quad = lane >> 4, lr = lane & 15;
  const int L0 = (quad & 1) * 32 + lr, L1 = L0 + 16;
  const bool selhi = (quad >> 1) != 0;
  const int xlr = (lr & 7) << 4;

  const char* qkvB = (const char*)qkvT;
  const char* projB = (const char*)projT;
  const int a0 = tid * 16;

  // staging offsets (loop-invariant): LDS dst byte for linear chunk byte a
  int ldsW[6];
#pragma unroll
  for (int i = 0; i < 6; ++i) {
    int a = a0 + i * 4096;
    int row = a / 384, col = a - row * 384;
    ldsW[i] = row * 384 + (col ^ ((row & 7) << 4));
  }

  // stage weight slab: global -> (transient regs) -> swizzled LDS, all
  // between the two barriers. No values live across the compute body.
  auto stage = [&](const char* src) {
    __syncthreads();                       // prior slab's readers done
#pragma unroll
    for (int i = 0; i < 6; ++i)
      *(uint4*)((char*)WtB + ldsW[i]) = *(const uint4*)(src + a0 + i * 4096);
    __syncthreads();                       // Wt ready
  };

  // Phase A: A-fragments of rolled window straight into registers
  bf8 af[6];
  {
    int token = wave * 16 + lr;
    int hs = (wh * 8 + (token >> 3) + SS) & 63;
    int ws2 = (wwi * 8 + (token & 7) + SS) & 63;
    const float* base = x + ((size_t)b * 4096 + hs * 64 + ws2) * 192 + quad * 8;
#pragma unroll
    for (int kc = 0; kc < 6; ++kc) {
      float4 lo = *(const float4*)(base + kc * 32);
      float4 hi = *(const float4*)(base + kc * 32 + 4);
      bf8 v;
      v[0] = (short)f2bf(lo.x); v[1] = (short)f2bf(lo.y);
      v[2] = (short)f2bf(lo.z); v[3] = (short)f2bf(lo.w);
      v[4] = (short)f2bf(hi.x); v[5] = (short)f2bf(hi.y);
      v[6] = (short)f2bf(hi.z); v[7] = (short)f2bf(hi.w);
      af[kc] = v;
    }
  }

  const float scale = 0.17677669529663687f;

  // Phase B1: Q slabs 0..2, SWAPPED GEMM -> qf frags (token = lr)
  bf8 qf[6];
  for (int s = 0; s < 3; ++s) {
    stage(qkvB + (size_t)s * 24576);
    f4 qa[4];
#pragma unroll
    for (int i = 0; i < 4; ++i) qa[i] = (f4){0.f, 0.f, 0.f, 0.f};
#pragma unroll
    for (int kc = 0; kc < 6; ++kc)
#pragma unroll
      for (int nt = 0; nt < 4; ++nt) {
        bf8 wf = LDSB(WtB, (nt * 16 + lr) * 384 + ((kc * 64 + quad * 16) ^ xlr));
        qa[nt] = __builtin_amdgcn_mfma_f32_16x16x32_bf16(wf, af[kc], qa[nt], 0, 0, 0);
      }
    unsigned pq[4][2];
#pragma unroll
    for (int nt = 0; nt < 4; ++nt) {
      float4 bv = *(const float4*)(qkv_b + s * 64 + nt * 16 + quad * 4);
      pq[nt][0] = pk2(qa[nt][0] + bv.x * scale, qa[nt][1] + bv.y * scale);
      pq[nt][1] = pk2(qa[nt][2] + bv.z * scale, qa[nt][3] + bv.w * scale);
    }
#pragma unroll
    for (int hh = 0; hh < 2; ++hh)
      qf[s * 2 + hh] = fragq(pq[hh * 2][0], pq[hh * 2][1],
                             pq[hh * 2 + 1][0], pq[hh * 2 + 1][1], L0, L1, selhi);
  }

  // Phase B2: K slabs 3..5, SWAPPED -> swizzled Ks[token][chan]
  for (int s = 0; s < 3; ++s) {
    stage(qkvB + (size_t)(s + 3) * 24576);
    f4 ka[4];
#pragma unroll
    for (int i = 0; i < 4; ++i) ka[i] = (f4){0.f, 0.f, 0.f, 0.f};
#pragma unroll
    for (int kc = 0; kc < 6; ++kc)
#pragma unroll
      for (int nt = 0; nt < 4; ++nt) {
        bf8 wf = LDSB(WtB, (nt * 16 + lr) * 384 + ((kc * 64 + quad * 16) ^ xlr));
        ka[nt] = __builtin_amdgcn_mfma_f32_16x16x32_bf16(wf, af[kc], ka[nt], 0, 0, 0);
      }
#pragma unroll
    for (int nt = 0; nt < 4; ++nt) {
      float4 bv = *(const float4*)(qkv_b + 192 + s * 64 + nt * 16 + quad * 4);
      uint2 st;
      st.x = pk2(ka[nt][0] + bv.x, ka[nt][1] + bv.y);
      st.y = pk2(ka[nt][2] + bv.z, ka[nt][3] + bv.w);
      *(uint2*)((char*)KsB + (wave * 16 + lr) * 384 +
                ((s * 128 + nt * 32 + quad * 8) ^ xlr)) = st;
    }
  }

  // Phase B3: V slabs 6..8, NORMAL -> swizzled Vt[chan][token]
  for (int s = 0; s < 3; ++s) {
    stage(qkvB + (size_t)(s + 6) * 24576);
    f4 va[4];
#pragma unroll
    for (int i = 0; i < 4; ++i) va[i] = (f4){0.f, 0.f, 0.f, 0.f};
#pragma unroll
    for (int kc = 0; kc < 6; ++kc)
#pragma unroll
      for (int nt = 0; nt < 4; ++nt) {
        bf8 wf = LDSB(WtB, (nt * 16 + lr) * 384 + ((kc * 64 + quad * 16) ^ xlr));
        va[nt] = __builtin_amdgcn_mfma_f32_16x16x32_bf16(af[kc], wf, va[nt], 0, 0, 0);
      }
#pragma unroll
    for (int nt = 0; nt < 4; ++nt) {
      float bias = qkv_b[384 + s * 64 + nt * 16 + lr];
      uint2 st;
      st.x = pk2(va[nt][0] + bias, va[nt][1] + bias);
      st.y = pk2(va[nt][2] + bias, va[nt][3] + bias);
      *(uint2*)((char*)VtB + (size_t)(s * 64 + nt * 16 + lr) * 128 +
                ((wave * 32 + quad * 8) ^ xlr)) = st;
    }
  }

  __syncthreads();   // Ks/Vt visible to all waves before attention

  // Phase C: attention, fully in-register softmax (query = lr)
  const int q_tok = wave * 16 + lr;
  const int qh3 = q_tok >> 3, qw3 = q_tok & 7;
  int lab_q;
  {
    int ph_r = wh * 8 + qh3, pw_r = wwi * 8 + qw3;
    lab_q = (ph_r < 56 ? 0 : (ph_r < 60 ? 1 : 2)) * 3 +
            (pw_r < 56 ? 0 : (pw_r < 60 ? 1 : 2));
  }
  int ridx[4][4]; float msk[4][4];
#pragma unroll
  for (int nt = 0; nt < 4; ++nt)
#pragma unroll
    for (int r = 0; r < 4; ++r) {
      int key = nt * 16 + quad * 4 + r;
      int kh = key >> 3, kw = key & 7;
      ridx[nt][r] = ((qh3 - kh + 7) * 15 + (qw3 - kw + 7)) * NH;
      int ph_c = wh * 8 + kh, pw_c = wwi * 8 + kw;
      int lab_k = (ph_c < 56 ? 0 : (ph_c < 60 ? 1 : 2)) * 3 +
                  (pw_c < 56 ? 0 : (pw_c < 60 ? 1 : 2));
      msk[nt][r] = (lab_q != lab_k) ? -100.f : 0.f;
    }

  unsigned obf[6][4];
#pragma unroll
  for (int h = 0; h < 6; ++h) {
    f4 sa[4];
#pragma unroll
    for (int i = 0; i < 4; ++i) sa[i] = (f4){0.f, 0.f, 0.f, 0.f};
#pragma unroll
    for (int nt = 0; nt < 4; ++nt) {
      bf8 kfr = LDSB(KsB, (nt * 16 + lr) * 384 + ((h * 64 + quad * 16) ^ xlr));
      sa[nt] = __builtin_amdgcn_mfma_f32_16x16x32_bf16(kfr, qf[h], sa[nt], 0, 0, 0);
    }
    float p[4][4]; float mx = -1e30f;
#pragma unroll
    for (int nt = 0; nt < 4; ++nt)
#pragma unroll
      for (int r = 0; r < 4; ++r) {
        float v = sa[nt][r] + rpb[ridx[nt][r] + h] + msk[nt][r];
        p[nt][r] = v; mx = fmaxf(mx, v);
      }
    mx = fmaxf(mx, __shfl_xor(mx, 16));
    mx = fmaxf(mx, __shfl_xor(mx, 32));
    float sum = 0.f;
#pragma unroll
    for (int nt = 0; nt < 4; ++nt)
#pragma unroll
      for (int r = 0; r < 4; ++r) {
        float e = __expf(p[nt][r] - mx);
        p[nt][r] = e; sum += e;
      }
    sum += __shfl_xor(sum, 16);
    sum += __shfl_xor(sum, 32);
    float inv = 1.f / sum;
    unsigned pp[4][2];
#pragma unroll
    for (int nt = 0; nt < 4; ++nt) {
      pp[nt][0] = pk2(p[nt][0] * inv, p[nt][1] * inv);
      pp[nt][1] = pk2(p[nt][2] * inv, p[nt][3] * inv);
    }
    f4 o0 = (f4){0.f, 0.f, 0.f, 0.f}, o1 = (f4){0.f, 0.f, 0.f, 0.f};
#pragma unroll
    for (int kc = 0; kc < 2; ++kc) {
      bf8 pf = fragq(pp[kc * 2][0], pp[kc * 2][1],
                     pp[kc * 2 + 1][0], pp[kc * 2 + 1][1], L0, L1, selhi);
      bf8 v0 = LDSB(VtB, (size_t)(h * 32 + lr) * 128 + ((kc * 64 + quad * 16) ^ xlr));
      bf8 v1 = LDSB(VtB, (size_t)(h * 32 + 16 + lr) * 128 + ((kc * 64 + quad * 16) ^ xlr));
      o0 = __builtin_amdgcn_mfma_f32_16x16x32_bf16(v0, pf, o0, 0, 0, 0);
      o1 = __builtin_amdgcn_mfma_f32_16x16x32_bf16(v1, pf, o1, 0, 0, 0);
    }
    obf[h][0] = pk2(o0[0], o0[1]); obf[h][1] = pk2(o0[2], o0[3]);
    obf[h][2] = pk2(o1[0], o1[1]); obf[h][3] = pk2(o1[2], o1[3]);
  }

  // Phase D: proj from register O; weight slabs staged per iteration
  bf8 of[6];
#pragma unroll
  for (int kc = 0; kc < 6; ++kc)
    of[kc] = fragq(obf[kc][0], obf[kc][1], obf[kc][2], obf[kc][3], L0, L1, selhi);

  for (int s3 = 0; s3 < 3; ++s3) {
    stage(projB + (size_t)s3 * 24576);
    f4 acc[4];
#pragma unroll
    for (int i = 0; i < 4; ++i) acc[i] = (f4){0.f, 0.f, 0.f, 0.f};
#pragma unroll
    for (int kc = 0; kc < 6; ++kc)
#pragma unroll
      for (int nt = 0; nt < 4; ++nt) {
        bf8 wf = LDSB(WtB, (nt * 16 + lr) * 384 + ((kc * 64 + quad * 16) ^ xlr));
        acc[nt] = __builtin_amdgcn_mfma_f32_16x16x32_bf16(of[kc], wf, acc[nt], 0, 0, 0);
      }
#pragma unroll
    for (int nt = 0; nt < 4; ++nt) {
      int c = s3 * 64 + nt * 16 + lr;
      float bias = proj_b[c];
#pragma unroll
      for (int r = 0; r < 4; ++r) {
        int row = wave * 16 + quad * 4 + r;
        int ho = (wh * 8 + (row >> 3) + SS) & 63;
        int wo = (wwi * 8 + (row & 7) + SS) & 63;
        size_t off = ((size_t)b * 4096 + ho * 64 + wo) * 192 + c;
        out[off] = acc[nt][r] + bias + x[off];
      }
    }
  }
}

// ---- K2: fused FC1+GELU+FC2+residual ----
// H register-resident (swapped FC1 + quad-permute); weight staging
// load-inside-barriers (no cross-slab prefetch registers -> no spills).
__global__ __launch_bounds__(256, 2) void k_mlp(
    const u16* __restrict__ fc1T, const float* __restrict__ fc1_b,
    const u16* __restrict__ fc2T, const float* __restrict__ fc2_b,
    float* __restrict__ out)
{
  __shared__ short Wl1[64 * 192];   // fc1 slab [n_local][k=192], swizzled
  __shared__ short Wl2[192 * 64];   // fc2 slab [n=192][k_local=64], swizzled

  const int blk = blockIdx.x;
  const int tid = threadIdx.x;
  const int wave = tid >> 6, lane = tid & 63, quad = lane >> 4, lr = lane & 15;
  const int L0 = (quad & 1) * 32 + lr, L1 = L0 + 16;
  const bool selhi = (quad >> 1) != 0;
  const int xlr = (lr & 7) << 4;
  const size_t r0 = (size_t)blk * 64;

  const char* fc1B = (const char*)fc1T;
  const char* fc2B = (const char*)fc2T;
  const int a0 = tid * 16;

  int lds1[6], lds2[6], g2[6];
#pragma unroll
  for (int i = 0; i < 6; ++i) {
    int A = a0 + i * 4096;
    int row = A / 384, col = A - row * 384;
    lds1[i] = row * 384 + (col ^ ((row & 7) << 4));
    int r2 = A >> 7, c2 = A & 127;
    g2[i] = r2 * 1536 + c2;
    lds2[i] = r2 * 128 + (c2 ^ ((r2 & 7) << 4));
  }

  // A-fragments of x1 straight from global (f32 -> bf16 regs)
  bf8 af[6];
  {
    const float* base = out + (r0 + wave * 16 + lr) * 192 + quad * 8;
#pragma unroll
    for (int kc = 0; kc < 6; ++kc) {
      float4 lo = *(const float4*)(base + kc * 32);
      float4 hi = *(const float4*)(base + kc * 32 + 4);
      bf8 v;
      v[0] = (short)f2bf(lo.x); v[1] = (short)f2bf(lo.y);
      v[2] = (short)f2bf(lo.z); v[3] = (short)f2bf(lo.w);
      v[4] = (short)f2bf(hi.x); v[5] = (short)f2bf(hi.y);
      v[6] = (short)f2bf(hi.z); v[7] = (short)f2bf(hi.w);
      af[kc] = v;
    }
  }

  f4 acc2[12];
#pragma unroll
  for (int i = 0; i < 12; ++i) acc2[i] = (f4){0.f, 0.f, 0.f, 0.f};

#pragma unroll 1
  for (int s = 0; s < 12; ++s) {
    __syncthreads();                    // previous slab's readers done
    // stage both slabs: global -> transient regs -> swizzled LDS
#pragma unroll
    for (int i = 0; i < 6; ++i)
      *(uint4*)((char*)Wl1 + lds1[i]) =
          *(const uint4*)(fc1B + (size_t)s * 24576 + a0 + i * 4096);
#pragma unroll
    for (int i = 0; i < 6; ++i)
      *(uint4*)((char*)Wl2 + lds2[i]) =
          *(const uint4*)(fc2B + (size_t)s * 128 + g2[i]);
    __syncthreads();                    // slab ready

    // FC1 slab, SWAPPED -> H^T[hchan][token=lr] in regs
    f4 ha[4];
#pragma unroll
    for (int i = 0; i < 4; ++i) ha[i] = (f4){0.f, 0.f, 0.f, 0.f};
#pragma unroll
    for (int kc = 0; kc < 6; ++kc)
#pragma unroll
      for (int nt = 0; nt < 4; ++nt) {
        bf8 wf = LDSB(Wl1, (nt * 16 + lr) * 384 + ((kc * 64 + quad * 16) ^ xlr));
        ha[nt] = __builtin_amdgcn_mfma_f32_16x16x32_bf16(wf, af[kc], ha[nt], 0, 0, 0);
      }
    unsigned hp[4][2];
#pragma unroll
    for (int nt = 0; nt < 4; ++nt) {
      float4 bv = *(const float4*)(fc1_b + s * 64 + nt * 16 + quad * 4);
      float g0 = gelu_exact(ha[nt][0] + bv.x);
      float g1 = gelu_exact(ha[nt][1] + bv.y);
      float g2_ = gelu_exact(ha[nt][2] + bv.z);
      float g3 = gelu_exact(ha[nt][3] + bv.w);
      hp[nt][0] = pk2(g0, g1);
      hp[nt][1] = pk2(g2_, g3);
    }
    // FC2 partial accumulation (H via quad-permute)
#pragma unroll
    for (int kc2 = 0; kc2 < 2; ++kc2) {
      bf8 hf = fragq(hp[kc2 * 2][0], hp[kc2 * 2][1],
                     hp[kc2 * 2 + 1][0], hp[kc2 * 2 + 1][1], L0, L1, selhi);
#pragma unroll
      for (int nto = 0; nto < 12; ++nto) {
        bf8 wf = LDSB(Wl2, (nto * 16 + lr) * 128 + ((kc2 * 64 + quad * 16) ^ xlr));
        acc2[nto] = __builtin_amdgcn_mfma_f32_16x16x32_bf16(hf, wf, acc2[nto], 0, 0, 0);
      }
    }
  }

  // epilogue: + bias + residual (f32 re-read), in-place
#pragma unroll
  for (int nt = 0; nt < 12; ++nt) {
    int c = nt * 16 + lr;
    float bias = fc2_b[c];
#pragma unroll
    for (int r = 0; r < 4; ++r) {
      int row = wave * 16 + quad * 4 + r;
      size_t off = (r0 + row) * 192 + c;
      out[off] = acc2[nt][r] + bias + out[off];
    }
  }
}

extern "C" void kernel_launch(void* const* d_in, const int* in_sizes, int n_in,
                              void* d_out, int out_size, void* d_ws, size_t ws_size,
                              hipStream_t stream)
{
  const float* x      = (const float*)d_in[0];
  const float* rpb    = (const float*)d_in[1];
  const float* qkv_w  = (const float*)d_in[2];
  const float* qkv_b  = (const float*)d_in[3];
  const float* proj_w = (const float*)d_in[4];
  const float* proj_b = (const float*)d_in[5];
  const float* fc1_w  = (const float*)d_in[6];
  const float* fc1_b  = (const float*)d_in[7];
  const float* fc2_w  = (const float*)d_in[8];
  const float* fc2_b  = (const float*)d_in[9];
  float* out = (float*)d_out;

  // bf16 transposed weights in workspace (885 KB total)
  u16* qkvT = (u16*)d_ws;                 // [576][192]
  u16* projT = qkvT + 576 * 192;          // [192][192]
  u16* fc1T  = projT + 192 * 192;         // [768][192]
  u16* fc2T  = fc1T + 768 * 192;          // [192][768]

  const float scale = 0.17677669529663687f;  // 32^-0.5 baked into W_q
  k_prep<<<108, 256, 0, stream>>>(qkv_w, qkvT, 192, 576, 192, scale);
  k_prep<<< 36, 256, 0, stream>>>(proj_w, projT, 192, 192, 0, 1.f);
  k_prep<<<144, 256, 0, stream>>>(fc1_w, fc1T, 192, 768, 0, 1.f);
  k_prep<<<144, 256, 0, stream>>>(fc2_w, fc2T, 768, 192, 0, 1.f);

  k_win<<<dim3(NWIN), 256, 0, stream>>>(x, qkvT, qkv_b, rpb, projT, proj_b, out);
  k_mlp<<<dim3(NWIN), 256, 0, stream>>>(fc1T, fc1_b, fc2T, fc2_b, out);
}

// Round 5
// 436.717 us; speedup vs baseline: 1.8226x; 1.3571x over previous
//
#include <hip/hip_runtime.h>

#define SS 4
#define NH 6
#define NWIN 2048

typedef unsigned short u16;
typedef __attribute__((ext_vector_type(8))) short bf8;
typedef __attribute__((ext_vector_type(4))) float f4;

__device__ __forceinline__ u16 f2bf(float f) {
  unsigned int x = __builtin_bit_cast(unsigned int, f);
  unsigned int r = x + 0x7fffu + ((x >> 16) & 1u);
  return (u16)(r >> 16);
}
__device__ __forceinline__ unsigned int pk2(float a, float b) {
  return (unsigned int)f2bf(a) | ((unsigned int)f2bf(b) << 16);
}

// Inline exact-GELU (Abramowitz-Stegun 7.1.26 erf, |err|<=1.5e-7): pure VALU.
__device__ __forceinline__ float gelu_exact(float v) {
  float u = v * 0.70710678118654752f;
  float a = __builtin_fabsf(u);
  float t = __builtin_amdgcn_rcpf(1.f + 0.3275911f * a);
  float poly = t * (0.254829592f + t * (-0.284496736f + t * (1.421413741f +
               t * (-1.453152027f + t * 1.061405429f))));
  float e = __expf(-a * a);
  float erf_a = 1.f - poly * e;
  float erf_u = (u < 0.f) ? -erf_a : erf_a;
  return 0.5f * v * (1.f + erf_u);
}

// LDS read helper: byte-offset addressing (offsets are 16B-aligned)
#define LDSB(base, off) (*(const bf8*)((const char*)(base) + (off)))

// Build an A/B-fragment (row = lr, k = quad*8 + e) from quad-transposed
// register state (verified-passing layout, r1).
__device__ __forceinline__ bf8 fragq(unsigned p00, unsigned p01,
                                     unsigned p10, unsigned p11,
                                     int L0, int L1, bool selhi) {
  unsigned a0 = (unsigned)__shfl((int)p00, L0);
  unsigned a1 = (unsigned)__shfl((int)p01, L0);
  unsigned b0 = (unsigned)__shfl((int)p10, L0);
  unsigned b1 = (unsigned)__shfl((int)p11, L0);
  unsigned c0 = (unsigned)__shfl((int)p00, L1);
  unsigned c1 = (unsigned)__shfl((int)p01, L1);
  unsigned d0 = (unsigned)__shfl((int)p10, L1);
  unsigned d1 = (unsigned)__shfl((int)p11, L1);
  uint4 t;
  t.x = selhi ? b0 : a0;
  t.y = selhi ? b1 : a1;
  t.z = selhi ? d0 : c0;
  t.w = selhi ? d1 : c1;
  return __builtin_bit_cast(bf8, t);
}

// ---- prep A: f32 [192][N] -> bf16 "LDS image": row n, byte col swizzled by
// ((n&7)<<4). LDS staging then becomes a LINEAR copy (global_load_lds-able);
// compute-side reads keep the existing XOR swizzle. ----
__global__ __launch_bounds__(256) void k_prep_row(
    const float* __restrict__ src, u16* __restrict__ dst,
    int N, int scale_n, float scale)
{
  int idx = blockIdx.x * 256 + threadIdx.x;
  int total = 48 * N;                 // 192/4 groups per row
  if (idx >= total) return;
  int n = idx % N;
  int kq = (idx / N) << 2;
  float s = (n < scale_n) ? scale : 1.f;
  ushort4 o;
  o.x = f2bf(src[(size_t)(kq + 0) * N + n] * s);
  o.y = f2bf(src[(size_t)(kq + 1) * N + n] * s);
  o.z = f2bf(src[(size_t)(kq + 2) * N + n] * s);
  o.w = f2bf(src[(size_t)(kq + 3) * N + n] * s);
  int byte_off = n * 384 + ((kq * 2) ^ ((n & 7) << 4));
  *(ushort4*)((char*)dst + byte_off) = o;
}

// ---- prep B: fc2_w f32 [768][192] -> fc2 LDS image: 12 slabs of 24576 B,
// slab s holds Wl2 rows [192][128B] (k-cols s*64..s*64+63), swizzled. ----
__global__ __launch_bounds__(256) void k_prep_fc2(
    const float* __restrict__ src, u16* __restrict__ dst)
{
  int idx = blockIdx.x * 256 + threadIdx.x;
  if (idx >= 192 * 192) return;       // 192 rows x 192 groups of 4 (768 k)
  int n = idx % 192;
  int kq = (idx / 192) << 2;
  ushort4 o;
  o.x = f2bf(src[(size_t)(kq + 0) * 192 + n]);
  o.y = f2bf(src[(size_t)(kq + 1) * 192 + n]);
  o.z = f2bf(src[(size_t)(kq + 2) * 192 + n]);
  o.w = f2bf(src[(size_t)(kq + 3) * 192 + n]);
  int cc = kq * 2;                    // byte col within the 1536B fc2T row
  int byte_off = (cc >> 7) * 24576 + n * 128 + ((cc & 127) ^ ((n & 7) << 4));
  *(ushort4*)((char*)dst + byte_off) = o;
}

// ---- K1: roll+partition+QKV+attention+proj+reverse+roll+residual ----
// Register-resident Q/P/O (swapped MFMA + quad-permute), K/V in swizzled LDS.
// Weight staging via global_load_lds (async DMA, linear dst, pre-swizzled
// source image): no VGPR round-trip, no spill risk. LDS 72KB -> 2 blocks/CU.
__global__ __launch_bounds__(256, 2) void k_win(
    const float* __restrict__ x, const u16* __restrict__ qkvT,
    const float* __restrict__ qkv_b, const float* __restrict__ rpb,
    const u16* __restrict__ projT, const float* __restrict__ proj_b,
    float* __restrict__ out)
{
  __shared__ short KsB[64 * 192];   // K [token][chan], rows 384B, XOR-swizzled
  __shared__ short VtB[192 * 64];   // V^T [chan][token], rows 128B, swizzled
  __shared__ short WtB[64 * 192];   // weight slab [n_local][k], swizzled image

  const int w = blockIdx.x;
  const int b = w >> 6, wh = (w >> 3) & 7, wwi = w & 7;
  const int tid = threadIdx.x;
  const int wave = tid >> 6, lane = tid & 63, quad = lane >> 4, lr = lane & 15;
  const int L0 = (quad & 1) * 32 + lr, L1 = L0 + 16;
  const bool selhi = (quad >> 1) != 0;
  const int xlr = (lr & 7) << 4;

  const char* qkvB = (const char*)qkvT;
  const char* projB = (const char*)projT;
  const int a0 = tid * 16;

  // stage weight slab: linear DMA global->LDS (image is pre-swizzled)
  auto stage = [&](const char* src) {
    __syncthreads();                       // prior slab's readers done
#pragma unroll
    for (int i = 0; i < 6; ++i)
      __builtin_amdgcn_global_load_lds(
          (const unsigned int*)(src + a0 + i * 4096),
          (unsigned int*)((char*)WtB + a0 + i * 4096), 16, 0, 0);
    __syncthreads();                       // drains vmcnt: Wt ready
  };

  // Phase A: A-fragments of rolled window straight into registers
  bf8 af[6];
  {
    int token = wave * 16 + lr;
    int hs = (wh * 8 + (token >> 3) + SS) & 63;
    int ws2 = (wwi * 8 + (token & 7) + SS) & 63;
    const float* base = x + ((size_t)b * 4096 + hs * 64 + ws2) * 192 + quad * 8;
#pragma unroll
    for (int kc = 0; kc < 6; ++kc) {
      float4 lo = *(const float4*)(base + kc * 32);
      float4 hi = *(const float4*)(base + kc * 32 + 4);
      bf8 v;
      v[0] = (short)f2bf(lo.x); v[1] = (short)f2bf(lo.y);
      v[2] = (short)f2bf(lo.z); v[3] = (short)f2bf(lo.w);
      v[4] = (short)f2bf(hi.x); v[5] = (short)f2bf(hi.y);
      v[6] = (short)f2bf(hi.z); v[7] = (short)f2bf(hi.w);
      af[kc] = v;
    }
  }

  const float scale = 0.17677669529663687f;

  // Phase B1: Q slabs 0..2, SWAPPED GEMM -> qf frags (token = lr)
  bf8 qf[6];
  for (int s = 0; s < 3; ++s) {
    stage(qkvB + (size_t)s * 24576);
    f4 qa[4];
#pragma unroll
    for (int i = 0; i < 4; ++i) qa[i] = (f4){0.f, 0.f, 0.f, 0.f};
#pragma unroll
    for (int kc = 0; kc < 6; ++kc)
#pragma unroll
      for (int nt = 0; nt < 4; ++nt) {
        bf8 wf = LDSB(WtB, (nt * 16 + lr) * 384 + ((kc * 64 + quad * 16) ^ xlr));
        qa[nt] = __builtin_amdgcn_mfma_f32_16x16x32_bf16(wf, af[kc], qa[nt], 0, 0, 0);
      }
    unsigned pq[4][2];
#pragma unroll
    for (int nt = 0; nt < 4; ++nt) {
      float4 bv = *(const float4*)(qkv_b + s * 64 + nt * 16 + quad * 4);
      pq[nt][0] = pk2(qa[nt][0] + bv.x * scale, qa[nt][1] + bv.y * scale);
      pq[nt][1] = pk2(qa[nt][2] + bv.z * scale, qa[nt][3] + bv.w * scale);
    }
#pragma unroll
    for (int hh = 0; hh < 2; ++hh)
      qf[s * 2 + hh] = fragq(pq[hh * 2][0], pq[hh * 2][1],
                             pq[hh * 2 + 1][0], pq[hh * 2 + 1][1], L0, L1, selhi);
  }

  // Phase B2: K slabs 3..5, SWAPPED -> swizzled Ks[token][chan]
  for (int s = 0; s < 3; ++s) {
    stage(qkvB + (size_t)(s + 3) * 24576);
    f4 ka[4];
#pragma unroll
    for (int i = 0; i < 4; ++i) ka[i] = (f4){0.f, 0.f, 0.f, 0.f};
#pragma unroll
    for (int kc = 0; kc < 6; ++kc)
#pragma unroll
      for (int nt = 0; nt < 4; ++nt) {
        bf8 wf = LDSB(WtB, (nt * 16 + lr) * 384 + ((kc * 64 + quad * 16) ^ xlr));
        ka[nt] = __builtin_amdgcn_mfma_f32_16x16x32_bf16(wf, af[kc], ka[nt], 0, 0, 0);
      }
#pragma unroll
    for (int nt = 0; nt < 4; ++nt) {
      float4 bv = *(const float4*)(qkv_b + 192 + s * 64 + nt * 16 + quad * 4);
      uint2 st;
      st.x = pk2(ka[nt][0] + bv.x, ka[nt][1] + bv.y);
      st.y = pk2(ka[nt][2] + bv.z, ka[nt][3] + bv.w);
      *(uint2*)((char*)KsB + (wave * 16 + lr) * 384 +
                ((s * 128 + nt * 32 + quad * 8) ^ xlr)) = st;
    }
  }

  // Phase B3: V slabs 6..8, NORMAL -> swizzled Vt[chan][token]
  for (int s = 0; s < 3; ++s) {
    stage(qkvB + (size_t)(s + 6) * 24576);
    f4 va[4];
#pragma unroll
    for (int i = 0; i < 4; ++i) va[i] = (f4){0.f, 0.f, 0.f, 0.f};
#pragma unroll
    for (int kc = 0; kc < 6; ++kc)
#pragma unroll
      for (int nt = 0; nt < 4; ++nt) {
        bf8 wf = LDSB(WtB, (nt * 16 + lr) * 384 + ((kc * 64 + quad * 16) ^ xlr));
        va[nt] = __builtin_amdgcn_mfma_f32_16x16x32_bf16(af[kc], wf, va[nt], 0, 0, 0);
      }
#pragma unroll
    for (int nt = 0; nt < 4; ++nt) {
      float bias = qkv_b[384 + s * 64 + nt * 16 + lr];
      uint2 st;
      st.x = pk2(va[nt][0] + bias, va[nt][1] + bias);
      st.y = pk2(va[nt][2] + bias, va[nt][3] + bias);
      *(uint2*)((char*)VtB + (size_t)(s * 64 + nt * 16 + lr) * 128 +
                ((wave * 32 + quad * 8) ^ xlr)) = st;
    }
  }

  __syncthreads();   // Ks/Vt visible to all waves before attention

  // Phase C: attention, fully in-register softmax (query = lr)
  const int q_tok = wave * 16 + lr;
  const int qh3 = q_tok >> 3, qw3 = q_tok & 7;
  int lab_q;
  {
    int ph_r = wh * 8 + qh3, pw_r = wwi * 8 + qw3;
    lab_q = (ph_r < 56 ? 0 : (ph_r < 60 ? 1 : 2)) * 3 +
            (pw_r < 56 ? 0 : (pw_r < 60 ? 1 : 2));
  }
  int ridx[4][4]; float msk[4][4];
#pragma unroll
  for (int nt = 0; nt < 4; ++nt)
#pragma unroll
    for (int r = 0; r < 4; ++r) {
      int key = nt * 16 + quad * 4 + r;
      int kh = key >> 3, kw = key & 7;
      ridx[nt][r] = ((qh3 - kh + 7) * 15 + (qw3 - kw + 7)) * NH;
      int ph_c = wh * 8 + kh, pw_c = wwi * 8 + kw;
      int lab_k = (ph_c < 56 ? 0 : (ph_c < 60 ? 1 : 2)) * 3 +
                  (pw_c < 56 ? 0 : (pw_c < 60 ? 1 : 2));
      msk[nt][r] = (lab_q != lab_k) ? -100.f : 0.f;
    }

  unsigned obf[6][4];
#pragma unroll
  for (int h = 0; h < 6; ++h) {
    f4 sa[4];
#pragma unroll
    for (int i = 0; i < 4; ++i) sa[i] = (f4){0.f, 0.f, 0.f, 0.f};
#pragma unroll
    for (int nt = 0; nt < 4; ++nt) {
      bf8 kfr = LDSB(KsB, (nt * 16 + lr) * 384 + ((h * 64 + quad * 16) ^ xlr));
      sa[nt] = __builtin_amdgcn_mfma_f32_16x16x32_bf16(kfr, qf[h], sa[nt], 0, 0, 0);
    }
    float p[4][4]; float mx = -1e30f;
#pragma unroll
    for (int nt = 0; nt < 4; ++nt)
#pragma unroll
      for (int r = 0; r < 4; ++r) {
        float v = sa[nt][r] + rpb[ridx[nt][r] + h] + msk[nt][r];
        p[nt][r] = v; mx = fmaxf(mx, v);
      }
    mx = fmaxf(mx, __shfl_xor(mx, 16));
    mx = fmaxf(mx, __shfl_xor(mx, 32));
    float sum = 0.f;
#pragma unroll
    for (int nt = 0; nt < 4; ++nt)
#pragma unroll
      for (int r = 0; r < 4; ++r) {
        float e = __expf(p[nt][r] - mx);
        p[nt][r] = e; sum += e;
      }
    sum += __shfl_xor(sum, 16);
    sum += __shfl_xor(sum, 32);
    float inv = 1.f / sum;
    unsigned pp[4][2];
#pragma unroll
    for (int nt = 0; nt < 4; ++nt) {
      pp[nt][0] = pk2(p[nt][0] * inv, p[nt][1] * inv);
      pp[nt][1] = pk2(p[nt][2] * inv, p[nt][3] * inv);
    }
    f4 o0 = (f4){0.f, 0.f, 0.f, 0.f}, o1 = (f4){0.f, 0.f, 0.f, 0.f};
#pragma unroll
    for (int kc = 0; kc < 2; ++kc) {
      bf8 pf = fragq(pp[kc * 2][0], pp[kc * 2][1],
                     pp[kc * 2 + 1][0], pp[kc * 2 + 1][1], L0, L1, selhi);
      bf8 v0 = LDSB(VtB, (size_t)(h * 32 + lr) * 128 + ((kc * 64 + quad * 16) ^ xlr));
      bf8 v1 = LDSB(VtB, (size_t)(h * 32 + 16 + lr) * 128 + ((kc * 64 + quad * 16) ^ xlr));
      o0 = __builtin_amdgcn_mfma_f32_16x16x32_bf16(v0, pf, o0, 0, 0, 0);
      o1 = __builtin_amdgcn_mfma_f32_16x16x32_bf16(v1, pf, o1, 0, 0, 0);
    }
    obf[h][0] = pk2(o0[0], o0[1]); obf[h][1] = pk2(o0[2], o0[3]);
    obf[h][2] = pk2(o1[0], o1[1]); obf[h][3] = pk2(o1[2], o1[3]);
  }

  // Phase D: proj from register O; weight slabs staged per iteration
  bf8 of[6];
#pragma unroll
  for (int kc = 0; kc < 6; ++kc)
    of[kc] = fragq(obf[kc][0], obf[kc][1], obf[kc][2], obf[kc][3], L0, L1, selhi);

  for (int s3 = 0; s3 < 3; ++s3) {
    stage(projB + (size_t)s3 * 24576);
    f4 acc[4];
#pragma unroll
    for (int i = 0; i < 4; ++i) acc[i] = (f4){0.f, 0.f, 0.f, 0.f};
#pragma unroll
    for (int kc = 0; kc < 6; ++kc)
#pragma unroll
      for (int nt = 0; nt < 4; ++nt) {
        bf8 wf = LDSB(WtB, (nt * 16 + lr) * 384 + ((kc * 64 + quad * 16) ^ xlr));
        acc[nt] = __builtin_amdgcn_mfma_f32_16x16x32_bf16(of[kc], wf, acc[nt], 0, 0, 0);
      }
#pragma unroll
    for (int nt = 0; nt < 4; ++nt) {
      int c = s3 * 64 + nt * 16 + lr;
      float bias = proj_b[c];
#pragma unroll
      for (int r = 0; r < 4; ++r) {
        int row = wave * 16 + quad * 4 + r;
        int ho = (wh * 8 + (row >> 3) + SS) & 63;
        int wo = (wwi * 8 + (row & 7) + SS) & 63;
        size_t off = ((size_t)b * 4096 + ho * 64 + wo) * 192 + c;
        out[off] = acc[nt][r] + bias + x[off];
      }
    }
  }
}

// ---- K2: fused FC1+GELU+FC2+residual ----
// H register-resident (swapped FC1 + quad-permute); weight staging via
// global_load_lds from pre-swizzled images (async DMA, no VGPR round-trip).
__global__ __launch_bounds__(256, 2) void k_mlp(
    const u16* __restrict__ fc1T, const float* __restrict__ fc1_b,
    const u16* __restrict__ fc2T, const float* __restrict__ fc2_b,
    float* __restrict__ out)
{
  __shared__ short Wl1[64 * 192];   // fc1 slab [n_local][k=192], swizzled image
  __shared__ short Wl2[192 * 64];   // fc2 slab [n=192][k_local=64], swizzled image

  const int blk = blockIdx.x;
  const int tid = threadIdx.x;
  const int wave = tid >> 6, lane = tid & 63, quad = lane >> 4, lr = lane & 15;
  const int L0 = (quad & 1) * 32 + lr, L1 = L0 + 16;
  const bool selhi = (quad >> 1) != 0;
  const int xlr = (lr & 7) << 4;
  const size_t r0 = (size_t)blk * 64;

  const char* fc1B = (const char*)fc1T;
  const char* fc2B = (const char*)fc2T;
  const int a0 = tid * 16;

  // A-fragments of x1 straight from global (f32 -> bf16 regs)
  bf8 af[6];
  {
    const float* base = out + (r0 + wave * 16 + lr) * 192 + quad * 8;
#pragma unroll
    for (int kc = 0; kc < 6; ++kc) {
      float4 lo = *(const float4*)(base + kc * 32);
      float4 hi = *(const float4*)(base + kc * 32 + 4);
      bf8 v;
      v[0] = (short)f2bf(lo.x); v[1] = (short)f2bf(lo.y);
      v[2] = (short)f2bf(lo.z); v[3] = (short)f2bf(lo.w);
      v[4] = (short)f2bf(hi.x); v[5] = (short)f2bf(hi.y);
      v[6] = (short)f2bf(hi.z); v[7] = (short)f2bf(hi.w);
      af[kc] = v;
    }
  }

  f4 acc2[12];
#pragma unroll
  for (int i = 0; i < 12; ++i) acc2[i] = (f4){0.f, 0.f, 0.f, 0.f};

#pragma unroll 1
  for (int s = 0; s < 12; ++s) {
    __syncthreads();                    // previous slab's readers done
#pragma unroll
    for (int i = 0; i < 6; ++i)
      __builtin_amdgcn_global_load_lds(
          (const unsigned int*)(fc1B + (size_t)s * 24576 + a0 + i * 4096),
          (unsigned int*)((char*)Wl1 + a0 + i * 4096), 16, 0, 0);
#pragma unroll
    for (int i = 0; i < 6; ++i)
      __builtin_amdgcn_global_load_lds(
          (const unsigned int*)(fc2B + (size_t)s * 24576 + a0 + i * 4096),
          (unsigned int*)((char*)Wl2 + a0 + i * 4096), 16, 0, 0);
    __syncthreads();                    // drains vmcnt: slab ready

    // FC1 slab, SWAPPED -> H^T[hchan][token=lr] in regs
    f4 ha[4];
#pragma unroll
    for (int i = 0; i < 4; ++i) ha[i] = (f4){0.f, 0.f, 0.f, 0.f};
#pragma unroll
    for (int kc = 0; kc < 6; ++kc)
#pragma unroll
      for (int nt = 0; nt < 4; ++nt) {
        bf8 wf = LDSB(Wl1, (nt * 16 + lr) * 384 + ((kc * 64 + quad * 16) ^ xlr));
        ha[nt] = __builtin_amdgcn_mfma_f32_16x16x32_bf16(wf, af[kc], ha[nt], 0, 0, 0);
      }
    unsigned hp[4][2];
#pragma unroll
    for (int nt = 0; nt < 4; ++nt) {
      float4 bv = *(const float4*)(fc1_b + s * 64 + nt * 16 + quad * 4);
      float g0 = gelu_exact(ha[nt][0] + bv.x);
      float g1 = gelu_exact(ha[nt][1] + bv.y);
      float g2_ = gelu_exact(ha[nt][2] + bv.z);
      float g3 = gelu_exact(ha[nt][3] + bv.w);
      hp[nt][0] = pk2(g0, g1);
      hp[nt][1] = pk2(g2_, g3);
    }
    // FC2 partial accumulation (H via quad-permute)
#pragma unroll
    for (int kc2 = 0; kc2 < 2; ++kc2) {
      bf8 hf = fragq(hp[kc2 * 2][0], hp[kc2 * 2][1],
                     hp[kc2 * 2 + 1][0], hp[kc2 * 2 + 1][1], L0, L1, selhi);
#pragma unroll
      for (int nto = 0; nto < 12; ++nto) {
        bf8 wf = LDSB(Wl2, (nto * 16 + lr) * 128 + ((kc2 * 64 + quad * 16) ^ xlr));
        acc2[nto] = __builtin_amdgcn_mfma_f32_16x16x32_bf16(hf, wf, acc2[nto], 0, 0, 0);
      }
    }
  }

  // epilogue: + bias + residual (f32 re-read), in-place
#pragma unroll
  for (int nt = 0; nt < 12; ++nt) {
    int c = nt * 16 + lr;
    float bias = fc2_b[c];
#pragma unroll
    for (int r = 0; r < 4; ++r) {
      int row = wave * 16 + quad * 4 + r;
      size_t off = (r0 + row) * 192 + c;
      out[off] = acc2[nt][r] + bias + out[off];
    }
  }
}

extern "C" void kernel_launch(void* const* d_in, const int* in_sizes, int n_in,
                              void* d_out, int out_size, void* d_ws, size_t ws_size,
                              hipStream_t stream)
{
  const float* x      = (const float*)d_in[0];
  const float* rpb    = (const float*)d_in[1];
  const float* qkv_w  = (const float*)d_in[2];
  const float* qkv_b  = (const float*)d_in[3];
  const float* proj_w = (const float*)d_in[4];
  const float* proj_b = (const float*)d_in[5];
  const float* fc1_w  = (const float*)d_in[6];
  const float* fc1_b  = (const float*)d_in[7];
  const float* fc2_w  = (const float*)d_in[8];
  const float* fc2_b  = (const float*)d_in[9];
  float* out = (float*)d_out;

  // bf16 weight LDS-images in workspace (885 KB total)
  u16* qkvT = (u16*)d_ws;                 // [576][384B] row-swizzled image
  u16* projT = qkvT + 576 * 192;          // [192][384B] image
  u16* fc1T  = projT + 192 * 192;         // [768][384B] image
  u16* fc2T  = fc1T + 768 * 192;          // 12 slabs x [192][128B] image

  const float scale = 0.17677669529663687f;  // 32^-0.5 baked into W_q
  k_prep_row<<<108, 256, 0, stream>>>(qkv_w, qkvT, 576, 192, scale);
  k_prep_row<<< 36, 256, 0, stream>>>(proj_w, projT, 192, 0, 1.f);
  k_prep_row<<<144, 256, 0, stream>>>(fc1_w, fc1T, 768, 0, 1.f);
  k_prep_fc2<<<144, 256, 0, stream>>>(fc2_w, fc2T);

  k_win<<<dim3(NWIN), 256, 0, stream>>>(x, qkvT, qkv_b, rpb, projT, proj_b, out);
  k_mlp<<<dim3(NWIN), 256, 0, stream>>>(fc1T, fc1_b, fc2T, fc2_b, out);
}